// Round 5
// baseline (984.564 us; speedup 1.0000x reference)
//
#include <hip/hip_runtime.h>
#include <hip/hip_bf16.h>
#include <stdint.h>
#include <math.h>

#define T_TOKENS 16384
#define DIM      512
#define NEXP     8
#define HID      2048

typedef __attribute__((ext_vector_type(8))) __bf16 bf16x8;
typedef __attribute__((ext_vector_type(16))) float f32x16;

__device__ __forceinline__ f32x16 mfma32(bf16x8 a, bf16x8 b, f32x16 c) {
  return __builtin_amdgcn_mfma_f32_32x32x16_bf16(a, b, c, 0, 0, 0);
}

// async global->LDS DMA, 16B/lane; LDS dest = wave-uniform base + lane*16
__device__ __forceinline__ void glds16(const __bf16* g, __bf16* l) {
  __builtin_amdgcn_global_load_lds((const __attribute__((address_space(1))) void*)g,
                                   (__attribute__((address_space(3))) void*)l, 16, 0, 0);
}

#define WAITVM(n) asm volatile("s_waitcnt vmcnt(" #n ")" ::: "memory")
#define WAITLGKM0 asm volatile("s_waitcnt lgkmcnt(0)" ::: "memory")
#define SBAR      asm volatile("s_barrier" ::: "memory")
#define SCHEDB    __builtin_amdgcn_sched_barrier(0)
#define ADV6(v)   v = ((v) == 5) ? 0 : ((v) + 1)

// ---- JAX threefry2x32, key = (0, 42) ----
__device__ __forceinline__ void threefry2x32(uint32_t k0, uint32_t k1,
                                             uint32_t x0, uint32_t x1,
                                             uint32_t* o0, uint32_t* o1) {
  uint32_t ks0 = k0, ks1 = k1, ks2 = k0 ^ k1 ^ 0x1BD11BDAu;
#define TF_ROT(v, d) (((v) << (d)) | ((v) >> (32 - (d))))
#define TF_ROUND(r) { x0 += x1; x1 = TF_ROT(x1, r); x1 ^= x0; }
  x0 += ks0; x1 += ks1;
  TF_ROUND(13) TF_ROUND(15) TF_ROUND(26) TF_ROUND(6)
  x0 += ks1; x1 += ks2 + 1u;
  TF_ROUND(17) TF_ROUND(29) TF_ROUND(16) TF_ROUND(24)
  x0 += ks2; x1 += ks0 + 2u;
  TF_ROUND(13) TF_ROUND(15) TF_ROUND(26) TF_ROUND(6)
  x0 += ks0; x1 += ks1 + 3u;
  TF_ROUND(17) TF_ROUND(29) TF_ROUND(16) TF_ROUND(24)
  x0 += ks1; x1 += ks2 + 4u;
  TF_ROUND(13) TF_ROUND(15) TF_ROUND(26) TF_ROUND(6)
  x0 += ks2; x1 += ks0 + 5u;
#undef TF_ROUND
#undef TF_ROT
  *o0 = x0; *o1 = x1;
}

// ---- XLA ErfInv32 (Giles polynomial) ----
__device__ __forceinline__ float erfinv_xla(float x) {
  float w = -log1pf(__fmul_rn(-x, x));
  float p;
  if (w < 5.0f) {
    w = __fadd_rn(w, -2.5f);
    p = 2.81022636e-08f;
    p = __fadd_rn(3.43273939e-07f, __fmul_rn(p, w));
    p = __fadd_rn(-3.5233877e-06f, __fmul_rn(p, w));
    p = __fadd_rn(-4.39150654e-06f, __fmul_rn(p, w));
    p = __fadd_rn(0.00021858087f, __fmul_rn(p, w));
    p = __fadd_rn(-0.00125372503f, __fmul_rn(p, w));
    p = __fadd_rn(-0.00417768164f, __fmul_rn(p, w));
    p = __fadd_rn(0.246640727f, __fmul_rn(p, w));
    p = __fadd_rn(1.50140941f, __fmul_rn(p, w));
  } else {
    w = __fadd_rn(sqrtf(w), -3.0f);
    p = -0.000200214257f;
    p = __fadd_rn(0.000100950558f, __fmul_rn(p, w));
    p = __fadd_rn(0.00134934322f, __fmul_rn(p, w));
    p = __fadd_rn(-0.00367342844f, __fmul_rn(p, w));
    p = __fadd_rn(0.00573950773f, __fmul_rn(p, w));
    p = __fadd_rn(-0.0076224613f, __fmul_rn(p, w));
    p = __fadd_rn(0.00943887047f, __fmul_rn(p, w));
    p = __fadd_rn(1.00167406f, __fmul_rn(p, w));
    p = __fadd_rn(2.83297682f, __fmul_rn(p, w));
  }
  return __fmul_rn(p, x);
}

__device__ __forceinline__ float jax_normal_at(uint32_t i) {
  uint32_t o0, o1;
  threefry2x32(0u, 42u, 0u, i, &o0, &o1);
  uint32_t bits = o0 ^ o1;
  float f = __fadd_rn(__uint_as_float((bits >> 9) | 0x3f800000u), -1.0f);
  const float lo = -0.99999994f;
  float u = fmaxf(lo, __fadd_rn(__fmul_rn(f, 2.0f), lo));
  return __fmul_rn(1.4142135623730951f, erfinv_xla(u));
}

// ---------------- Router: 4 tokens per wave, 16 lanes per token ----------------
__global__ __launch_bounds__(256) void router_kernel(
    const float* __restrict__ x, const float* __restrict__ Wr, const float* __restrict__ br,
    const float* __restrict__ Wn, const float* __restrict__ bn,
    int* __restrict__ counts, int* __restrict__ top_i, float* __restrict__ top_g) {
  __shared__ float WrS[4224], WnS[4224];   // 512*8 + 16*8 pad
  const int tid = threadIdx.x;
#pragma unroll
  for (int i = 0; i < 4; ++i) {
    int i4 = tid + i * 256;                // float4 index 0..1023
    int d = i4 >> 1, eh = (i4 & 1) * 4;
    float4 vr = ((const float4*)Wr)[i4];
    float4 vn = ((const float4*)Wn)[i4];
    *(float4*)&WrS[d * 8 + (d >> 5) * 8 + eh] = vr;
    *(float4*)&WnS[d * 8 + (d >> 5) * 8 + eh] = vn;
  }
  __syncthreads();

  const int w = tid >> 6, lane = tid & 63;
  const int tl = lane & 3, dq = lane >> 2;     // token-in-wave, d-slice
  const int t = blockIdx.x * 16 + w * 4 + tl;

  const float* xp = x + (size_t)t * DIM + dq * 32;
  float xv[32];
#pragma unroll
  for (int i = 0; i < 8; ++i) {
    float4 f = *(const float4*)(xp + i * 4);
    xv[i * 4 + 0] = f.x; xv[i * 4 + 1] = f.y; xv[i * 4 + 2] = f.z; xv[i * 4 + 3] = f.w;
  }

  double accR[8], accN[8];
#pragma unroll
  for (int e2 = 0; e2 < 8; ++e2) { accR[e2] = 0.0; accN[e2] = 0.0; }

#pragma unroll
  for (int r = 0; r < 32; ++r) {
    int d = dq * 32 + r;
    const float* wr = &WrS[d * 8 + (d >> 5) * 8];
    const float* wn = &WnS[d * 8 + (d >> 5) * 8];
    double xd = (double)xv[r];
#pragma unroll
    for (int e2 = 0; e2 < 8; ++e2) {
      accR[e2] += xd * (double)wr[e2];
      accN[e2] += xd * (double)wn[e2];
    }
  }
#pragma unroll
  for (int m = 4; m <= 32; m <<= 1) {
#pragma unroll
    for (int e2 = 0; e2 < 8; ++e2) {
      accR[e2] += __shfl_xor(accR[e2], m);
      accN[e2] += __shfl_xor(accN[e2], m);
    }
  }

  const int el = (lane >> 2) & 7;
  double accRm = 0.0, accNm = 0.0;
#pragma unroll
  for (int e2 = 0; e2 < 8; ++e2) {
    double vR = __shfl(accR[e2], tl);
    double vN = __shfl(accN[e2], tl);
    if (e2 == el) { accRm = vR; accNm = vN; }
  }
  double noisy = -1.0e308;
  if (lane < 32) {
    double logit = accRm + (double)br[el];
    double nlin  = accNm + (double)bn[el];
    double noise = (double)jax_normal_at((uint32_t)t * 8u + (uint32_t)el);
    double sp = fmax(nlin, 0.0) + log1p(exp(-fabs(nlin)));
    noisy = logit + noise * sp;
  }
  double v[8];
#pragma unroll
  for (int e2 = 0; e2 < 8; ++e2) v[e2] = __shfl(noisy, tl + 4 * e2);

  if (lane < 4) {
    int i1 = 0; double v1 = v[0];
#pragma unroll
    for (int e2 = 1; e2 < 8; ++e2) if (v[e2] > v1) { v1 = v[e2]; i1 = e2; }
    int i2 = -1; double v2 = -1.0e308;
#pragma unroll
    for (int e2 = 0; e2 < 8; ++e2) if (e2 != i1 && v[e2] > v2) { v2 = v[e2]; i2 = e2; }
    double w2 = exp(v2 - v1);
    double s = 1.0 + w2;
    float g1 = (float)(1.0 / s), g2 = (float)(w2 / s);
    top_i[t * 2 + 0] = i1; top_g[t * 2 + 0] = g1;
    top_i[t * 2 + 1] = i2; top_g[t * 2 + 1] = g2;
    atomicAdd(&counts[i1], 1);
    atomicAdd(&counts[i2], 1);
  }
}

// scatter with inline exclusive scan (offsets 64-aligned so tiles never span experts)
__global__ __launch_bounds__(256) void scatter_kernel(
    const int* __restrict__ top_i, const float* __restrict__ top_g,
    const int* __restrict__ counts, int* __restrict__ fill,
    int* __restrict__ ltok, float* __restrict__ lgate) {
  int i = blockIdx.x * 256 + threadIdx.x;
  int e = top_i[i];
  float g = top_g[i];
  int off = 0;
#pragma unroll
  for (int j = 0; j < NEXP; ++j) {
    int c = (counts[j] + 63) & ~63;
    if (j < e) off += c;
  }
  int pos = atomicAdd(&fill[e], 1);
  int dst = off + pos;
  ltok[dst] = i >> 1;
  lgate[dst] = g;
}

// ---- transpose-pack for 32-wide MFMA fragment tiles:
// src [e][R][C] fp32 -> dst [e][C/32][R/8][32][8] bf16
// dst[e][nt][ko][lc][j] = src[e][ko*8+j][nt*32+lc]
__global__ __launch_bounds__(256) void pack_bfrag32(const float* __restrict__ src,
                                                    __bf16* __restrict__ dst,
                                                    int R, int C) {
  int nct = C >> 6;
  int tilesPerE = (R >> 6) * nct;
  int e = blockIdx.x / tilesPerE;
  int rem = blockIdx.x % tilesPerE;
  int rt = rem / nct, ct = rem % nct;

  __shared__ float Ls[64][68];

  const float* s = src + (size_t)e * R * C + (size_t)(rt * 64) * C + ct * 64;
  int row = threadIdx.x >> 4;
  int col = (threadIdx.x & 15) * 4;
#pragma unroll
  for (int it = 0; it < 4; ++it) {
    float4 v = *(const float4*)(s + (size_t)(it * 16 + row) * C + col);
    *(float4*)&Ls[it * 16 + row][col] = v;
  }
  __syncthreads();

  int KO = R >> 3;
#pragma unroll
  for (int q = 0; q < 2; ++q) {
    int f = threadIdx.x + q * 256;
    int lc = f & 31;
    int kol = (f >> 5) & 7;
    int ntl = f >> 8;
    bf16x8 v;
#pragma unroll
    for (int j = 0; j < 8; ++j) v[j] = (__bf16)Ls[kol * 8 + j][ntl * 32 + lc];
    size_t idx = ((size_t)(e * (C >> 5) + ct * 2 + ntl) * KO + rt * 8 + kol) * 256 + lc * 8;
    *(bf16x8*)(dst + idx) = v;
  }
}

// ---------------- Fused MFMA expert FFN v5 ------------------------------------
// M=64 tokens/block, 8 waves. Deep wave-private DMA pipeline: 1KB stages
// (one glds16 = one k-step of one 32-wide n-tile), ring of 6 slots/wave,
// counted s_waitcnt vmcnt(5) -> lead = 5 stages (~2.5x R3's lead).
// LDS layouts are [k-octet][token] linear (no swizzle): MFMA-feed ds_reads are
// half-wave-contiguous = conflict-free; staging writes eat the (rare) conflicts.
__global__ __launch_bounds__(512) void expert_mfma(
    const float* __restrict__ x,
    const __bf16* __restrict__ W1p, const float* __restrict__ b1,
    const __bf16* __restrict__ W2p, const float* __restrict__ b2,
    const int* __restrict__ counts,
    const int* __restrict__ ltok, const float* __restrict__ lgate,
    float* __restrict__ out) {
  const int e = blockIdx.x & 7;          // XCD-pinned expert
  const int tslot = blockIdx.x >> 3;     // 0..63

  __shared__ __bf16 Xs[64 * 512];        // 64 KB  [ko 0..63][tok 0..63][j 0..7]
  __shared__ __bf16 Hs[32 * 512];        // 32 KB  [ko2 0..31][tok][j]
  __shared__ __bf16 Ring[8][6][512];     // 48 KB  6 x 1KB slots per wave
  __shared__ int   toks[64];
  __shared__ float gates[64];

  const int tid  = threadIdx.x;
  const int lane = tid & 63;
  const int w    = tid >> 6;
  const int hi   = lane >> 5;
  const int lm   = lane & 31;

  int cnt = 0, off = 0;
#pragma unroll
  for (int j = 0; j < NEXP; ++j) {
    int c = counts[j];
    if (j == e) cnt = c;
    if (j < e) off += (c + 63) & ~63;
  }

  const __bf16* W1e = W1p + (size_t)e * (64 * 64 * 256);
  const __bf16* W2e = W2p + (size_t)e * (16 * 256 * 256);
  __bf16* ringW = &Ring[w][0][0];

  // wave-constant DMA source bases (lane offset folded in)
  // G1 stage (hc, ks):    g1b + hc*131072 + ks*512   (n-tile = hc*8+w, k-step ks)
  // G2 stage (hc, ks2,t): g2b + hc*8192 + t*65536 + ks2*512  (d-tile = 2w+t)
  const __bf16* g1b = W1e + (size_t)(w * 64) * 256 + lane * 8;
  const __bf16* g2b = W2e + (size_t)(2 * w) * 65536 + lane * 8;

  const float b2r0 = b2[e * DIM + (2 * w + 0) * 32 + lm];
  const float b2r1 = b2[e * DIM + (2 * w + 1) * 32 + lm];

  for (int tile = tslot; tile * 64 < cnt; tile += 64) {
    int start = tile * 64;
    int nrow = min(64, cnt - start);
    int base = off + start;

    // pre-issue first 5 stages (G1 hc=0, ks=0..4) into slots 0..4
#pragma unroll
    for (int pp = 0; pp < 5; ++pp) glds16(g1b + pp * 512, ringW + pp * 512);
    int is_ = 5, cs = 0;

    SBAR;                                // prev tile's epilogue done with toks/gates
    if (tid < 64) {
      int tk = 0; float g = 0.f;
      if (tid < nrow) { tk = ltok[base + tid]; g = lgate[base + tid]; }
      toks[tid] = tk; gates[tid] = g;
    }
    WAITLGKM0; SBAR;

    // stage X tile: fp32 global -> bf16 LDS [ko][tok][j]
    {
      int tm = tid >> 3, seg = tid & 7;
      bool valid = tm < nrow;
      const float* xp = x + (size_t)(valid ? toks[tm] : toks[0]) * DIM + seg * 64;
#pragma unroll
      for (int s2 = 0; s2 < 8; ++s2) {
        bf16x8 v;
        if (valid) {
          float4 f0 = *(const float4*)(xp + s2 * 8);
          float4 f1 = *(const float4*)(xp + s2 * 8 + 4);
          v[0] = (__bf16)f0.x; v[1] = (__bf16)f0.y; v[2] = (__bf16)f0.z; v[3] = (__bf16)f0.w;
          v[4] = (__bf16)f1.x; v[5] = (__bf16)f1.y; v[6] = (__bf16)f1.z; v[7] = (__bf16)f1.w;
        } else {
#pragma unroll
          for (int j = 0; j < 8; ++j) v[j] = (__bf16)0.f;
        }
        *(bf16x8*)&Xs[(size_t)(seg * 8 + s2) * 512 + tm * 8] = v;
      }
    }
    WAITLGKM0; SBAR;                     // Xs ready

    f32x16 acc200, acc201, acc210, acc211;
#pragma unroll
    for (int r = 0; r < 16; ++r) { acc200[r] = 0.f; acc201[r] = 0.f; acc210[r] = 0.f; acc211[r] = 0.f; }

    for (int hc = 0; hc < 8; ++hc) {
      float bias = b1[e * HID + (hc * 8 + w) * 32 + lm];
      f32x16 acc10, acc11;
#pragma unroll
      for (int r = 0; r < 16; ++r) { acc10[r] = 0.f; acc11[r] = 0.f; }

      // ---- GEMM1: 32 k-step stages ----
#pragma unroll
      for (int ss = 0; ss < 32; ++ss) {
        if (ss < 27) {
          glds16(g1b + (size_t)hc * 131072 + (ss + 5) * 512, ringW + is_ * 512); ADV6(is_);
        } else {       // last 5: prefetch this hc's first 5 GEMM2 stages
          int idx = ss - 27;             // (ks2 = idx>>1, t = idx&1)
          glds16(g2b + (size_t)hc * 8192 + (idx & 1) * 65536 + (idx >> 1) * 512,
                 ringW + is_ * 512); ADV6(is_);
        }
        WAITVM(5); SCHEDB;
        const __bf16* rb = ringW + cs * 512; ADV6(cs);
        bf16x8 a0 = *(const bf16x8*)&Xs[(size_t)(ss * 2 + hi) * 512 + lm * 8];
        bf16x8 a1 = *(const bf16x8*)&Xs[(size_t)(ss * 2 + hi) * 512 + 256 + lm * 8];
        bf16x8 b  = *(const bf16x8*)&rb[hi * 256 + lm * 8];
        __builtin_amdgcn_s_setprio(1);
        acc10 = mfma32(a0, b, acc10);
        acc11 = mfma32(a1, b, acc11);
        __builtin_amdgcn_s_setprio(0);
      }

      // ---- bias + relu -> Hs [ko2][tok][j] ----
#pragma unroll
      for (int m = 0; m < 2; ++m)
#pragma unroll
        for (int r = 0; r < 16; ++r) {
          int tok = (r & 3) + 8 * (r >> 2) + 4 * hi + 32 * m;
          float v = fmaxf((m ? acc11[r] : acc10[r]) + bias, 0.f);
          Hs[(size_t)(w * 4 + (lm >> 3)) * 512 + tok * 8 + (lm & 7)] = (__bf16)v;
        }
      WAITLGKM0; SBAR;                   // Hs ready for all waves

      // ---- GEMM2: 16 k-steps x 2 d-tiles = 32 stages ----
#pragma unroll
      for (int ks2 = 0; ks2 < 16; ++ks2) {
        bf16x8 h0 = *(const bf16x8*)&Hs[(size_t)(ks2 * 2 + hi) * 512 + lm * 8];
        bf16x8 h1 = *(const bf16x8*)&Hs[(size_t)(ks2 * 2 + hi) * 512 + 256 + lm * 8];
#pragma unroll
        for (int t = 0; t < 2; ++t) {
          const int uu = ks2 * 2 + t;
          if (uu < 27) {
            int nx = uu + 5;
            glds16(g2b + (size_t)hc * 8192 + (nx & 1) * 65536 + (nx >> 1) * 512,
                   ringW + is_ * 512); ADV6(is_);
            WAITVM(5);
          } else if (hc < 7) {           // prefetch next hc's first 5 GEMM1 stages
            int k2 = uu - 27;
            glds16(g1b + (size_t)(hc + 1) * 131072 + k2 * 512, ringW + is_ * 512); ADV6(is_);
            WAITVM(5);
          } else {                       // final drain of the tile
            if (uu == 27)      { WAITVM(4); }
            else if (uu == 28) { WAITVM(3); }
            else if (uu == 29) { WAITVM(2); }
            else if (uu == 30) { WAITVM(1); }
            else               { WAITVM(0); }
          }
          SCHEDB;
          const __bf16* rb = ringW + cs * 512; ADV6(cs);
          bf16x8 bfr = *(const bf16x8*)&rb[hi * 256 + lm * 8];
          __builtin_amdgcn_s_setprio(1);
          if (t == 0) {
            acc200 = mfma32(h0, bfr, acc200);
            acc201 = mfma32(h1, bfr, acc201);
          } else {
            acc210 = mfma32(h0, bfr, acc210);
            acc211 = mfma32(h1, bfr, acc211);
          }
          __builtin_amdgcn_s_setprio(0);
        }
      }
      SBAR;                              // all waves done reading Hs before rewrite
    }

    // ---- epilogue: gate-weighted atomic accumulate, d-coalesced ----
    {
      int d0 = (2 * w) * 32 + lm;
      int d1 = (2 * w + 1) * 32 + lm;
#pragma unroll
      for (int m = 0; m < 2; ++m)
#pragma unroll
        for (int r = 0; r < 16; ++r) {
          int row = (r & 3) + 8 * (r >> 2) + 4 * hi + 32 * m;
          int tk = toks[row];
          float gg = gates[row];
          float* op = out + (size_t)tk * DIM;
          atomicAdd(op + d0, gg * ((m ? acc201[r] : acc200[r]) + b2r0));
          atomicAdd(op + d1, gg * ((m ? acc211[r] : acc210[r]) + b2r1));
        }
    }
  }
}

extern "C" void kernel_launch(void* const* d_in, const int* in_sizes, int n_in,
                              void* d_out, int out_size, void* d_ws, size_t ws_size,
                              hipStream_t stream) {
  const float* x  = (const float*)d_in[0];
  const float* Wr = (const float*)d_in[1];
  const float* br = (const float*)d_in[2];
  const float* Wn = (const float*)d_in[3];
  const float* bn = (const float*)d_in[4];
  const float* W1 = (const float*)d_in[5];
  const float* b1 = (const float*)d_in[6];
  const float* W2 = (const float*)d_in[7];
  const float* b2 = (const float*)d_in[8];
  float* out = (float*)d_out;

  uint8_t* wsb = (uint8_t*)d_ws;
  int* counts   = (int*)(wsb);
  int* fill     = (int*)(wsb + 64);
  int* top_i    = (int*)(wsb + 128);      // 131072 B
  float* top_g  = (float*)(wsb + 131200); // 131072 B
  int* ltok     = (int*)(wsb + 262272);   // 133120 B (33280 slots, 64-align pad)
  float* lgate  = (float*)(wsb + 395392); // 133120 B
  __bf16* W1p   = (__bf16*)(wsb + 528896);            // 16 MB
  __bf16* W2p   = (__bf16*)(wsb + 528896 + 16777216); // 16 MB
  // total ws usage: 528896 + 2*16777216 = 34,083,328 bytes (~34.1 MB)

  hipMemsetAsync(out, 0, (size_t)out_size * sizeof(float), stream);
  hipMemsetAsync(wsb, 0, 128, stream);

  pack_bfrag32<<<2048, 256, 0, stream>>>(W1, W1p, DIM, HID);
  pack_bfrag32<<<2048, 256, 0, stream>>>(W2, W2p, HID, DIM);
  router_kernel<<<T_TOKENS / 16, 256, 0, stream>>>(x, Wr, br, Wn, bn, counts, top_i, top_g);
  scatter_kernel<<<(2 * T_TOKENS) / 256, 256, 0, stream>>>(top_i, top_g, counts, fill, ltok, lgate);
  expert_mfma<<<512, 512, 0, stream>>>(x, W1p, b1, W2p, b2, counts, ltok, lgate, out);
}

// Round 6
// 671.875 us; speedup vs baseline: 1.4654x; 1.4654x over previous
//
#include <hip/hip_runtime.h>
#include <hip/hip_bf16.h>
#include <stdint.h>
#include <math.h>

#define T_TOKENS 16384
#define DIM      512
#define NEXP     8
#define HID      2048
#define ECAP     6144   // fixed per-expert slot capacity (64-aligned)

typedef __attribute__((ext_vector_type(8))) __bf16 bf16x8;
typedef __attribute__((ext_vector_type(16))) float f32x16;

__device__ __forceinline__ f32x16 mfma32(bf16x8 a, bf16x8 b, f32x16 c) {
  return __builtin_amdgcn_mfma_f32_32x32x16_bf16(a, b, c, 0, 0, 0);
}

// async global->LDS DMA, 16B/lane; LDS dest = wave-uniform base + lane*16
__device__ __forceinline__ void glds16(const __bf16* g, __bf16* l) {
  __builtin_amdgcn_global_load_lds((const __attribute__((address_space(1))) void*)g,
                                   (__attribute__((address_space(3))) void*)l, 16, 0, 0);
}

#define WAITVM(n) asm volatile("s_waitcnt vmcnt(" #n ")" ::: "memory")
#define WAITLGKM0 asm volatile("s_waitcnt lgkmcnt(0)" ::: "memory")
#define SBAR      asm volatile("s_barrier" ::: "memory")
#define SCHEDB    __builtin_amdgcn_sched_barrier(0)
#define ADV3(v)   v = ((v) == 2) ? 0 : ((v) + 1)

// ---- JAX threefry2x32, key = (0, 42) ----
__device__ __forceinline__ void threefry2x32(uint32_t k0, uint32_t k1,
                                             uint32_t x0, uint32_t x1,
                                             uint32_t* o0, uint32_t* o1) {
  uint32_t ks0 = k0, ks1 = k1, ks2 = k0 ^ k1 ^ 0x1BD11BDAu;
#define TF_ROT(v, d) (((v) << (d)) | ((v) >> (32 - (d))))
#define TF_ROUND(r) { x0 += x1; x1 = TF_ROT(x1, r); x1 ^= x0; }
  x0 += ks0; x1 += ks1;
  TF_ROUND(13) TF_ROUND(15) TF_ROUND(26) TF_ROUND(6)
  x0 += ks1; x1 += ks2 + 1u;
  TF_ROUND(17) TF_ROUND(29) TF_ROUND(16) TF_ROUND(24)
  x0 += ks2; x1 += ks0 + 2u;
  TF_ROUND(13) TF_ROUND(15) TF_ROUND(26) TF_ROUND(6)
  x0 += ks0; x1 += ks1 + 3u;
  TF_ROUND(17) TF_ROUND(29) TF_ROUND(16) TF_ROUND(24)
  x0 += ks1; x1 += ks2 + 4u;
  TF_ROUND(13) TF_ROUND(15) TF_ROUND(26) TF_ROUND(6)
  x0 += ks2; x1 += ks0 + 5u;
#undef TF_ROUND
#undef TF_ROT
  *o0 = x0; *o1 = x1;
}

// ---- XLA ErfInv32 (Giles polynomial) ----
__device__ __forceinline__ float erfinv_xla(float x) {
  float w = -log1pf(__fmul_rn(-x, x));
  float p;
  if (w < 5.0f) {
    w = __fadd_rn(w, -2.5f);
    p = 2.81022636e-08f;
    p = __fadd_rn(3.43273939e-07f, __fmul_rn(p, w));
    p = __fadd_rn(-3.5233877e-06f, __fmul_rn(p, w));
    p = __fadd_rn(-4.39150654e-06f, __fmul_rn(p, w));
    p = __fadd_rn(0.00021858087f, __fmul_rn(p, w));
    p = __fadd_rn(-0.00125372503f, __fmul_rn(p, w));
    p = __fadd_rn(-0.00417768164f, __fmul_rn(p, w));
    p = __fadd_rn(0.246640727f, __fmul_rn(p, w));
    p = __fadd_rn(1.50140941f, __fmul_rn(p, w));
  } else {
    w = __fadd_rn(sqrtf(w), -3.0f);
    p = -0.000200214257f;
    p = __fadd_rn(0.000100950558f, __fmul_rn(p, w));
    p = __fadd_rn(0.00134934322f, __fmul_rn(p, w));
    p = __fadd_rn(-0.00367342844f, __fmul_rn(p, w));
    p = __fadd_rn(0.00573950773f, __fmul_rn(p, w));
    p = __fadd_rn(-0.0076224613f, __fmul_rn(p, w));
    p = __fadd_rn(0.00943887047f, __fmul_rn(p, w));
    p = __fadd_rn(1.00167406f, __fmul_rn(p, w));
    p = __fadd_rn(2.83297682f, __fmul_rn(p, w));
  }
  return __fmul_rn(p, x);
}

__device__ __forceinline__ float jax_normal_at(uint32_t i) {
  uint32_t o0, o1;
  threefry2x32(0u, 42u, 0u, i, &o0, &o1);
  uint32_t bits = o0 ^ o1;
  float f = __fadd_rn(__uint_as_float((bits >> 9) | 0x3f800000u), -1.0f);
  const float lo = -0.99999994f;
  float u = fmaxf(lo, __fadd_rn(__fmul_rn(f, 2.0f), lo));
  return __fmul_rn(1.4142135623730951f, erfinv_xla(u));
}

// ---------------- prep: zero out + zero fill + pack W1/W2 (one dispatch) ----
__global__ __launch_bounds__(256) void prep_kernel(
    const float* __restrict__ W1, const float* __restrict__ W2,
    __bf16* __restrict__ W1p, __bf16* __restrict__ W2p,
    float* __restrict__ out, int* __restrict__ fill) {
  const int tid = threadIdx.x;
  const int v = blockIdx.x;           // 0..4095

  // zero out: 2,097,152 float4 over 1,048,576 threads
  {
    float4 z = {0.f, 0.f, 0.f, 0.f};
    size_t g = (size_t)v * 256 + tid;
    ((float4*)out)[g] = z;
    ((float4*)out)[g + 1048576] = z;
  }
  if (v == 0 && tid < 8) fill[tid] = 0;

  // transpose-pack: dst[e][nt][ko][lc][j] = src[e][ko*8+j][nt*32+lc]
  const float* src; __bf16* dst; int R, C, e, rt, ct;
  if (v < 2048) { e = v >> 8; int rem = v & 255; rt = rem >> 5; ct = rem & 31;
                  src = W1; dst = W1p; R = 512; C = 2048; }
  else          { int v2 = v - 2048; e = v2 >> 8; int rem = v2 & 255; rt = rem >> 3; ct = rem & 7;
                  src = W2; dst = W2p; R = 2048; C = 512; }

  __shared__ float Ls[64][68];
  const float* s = src + (size_t)e * R * C + (size_t)(rt * 64) * C + ct * 64;
  int row = tid >> 4, col = (tid & 15) * 4;
#pragma unroll
  for (int it = 0; it < 4; ++it)
    *(float4*)&Ls[it * 16 + row][col] = *(const float4*)(s + (size_t)(it * 16 + row) * C + col);
  __syncthreads();

  int KO = R >> 3;
#pragma unroll
  for (int q = 0; q < 2; ++q) {
    int f = tid + q * 256;
    int lc = f & 31, kol = (f >> 5) & 7, ntl = f >> 8;
    bf16x8 vv;
#pragma unroll
    for (int j = 0; j < 8; ++j) vv[j] = (__bf16)Ls[kol * 8 + j][ntl * 32 + lc];
    size_t idx = ((size_t)(e * (C >> 5) + ct * 2 + ntl) * KO + rt * 8 + kol) * 256 + lc * 8;
    *(bf16x8*)(dst + idx) = vv;
  }
}

// ---------------- Router + scatter fused (fixed-capacity slots) ----------------
__global__ __launch_bounds__(256) void router_kernel(
    const float* __restrict__ x, const float* __restrict__ Wr, const float* __restrict__ br,
    const float* __restrict__ Wn, const float* __restrict__ bn,
    int* __restrict__ fill, int* __restrict__ ltok, float* __restrict__ lgate) {
  __shared__ float WrS[4224], WnS[4224];   // 512*8 + 16*8 pad
  const int tid = threadIdx.x;
#pragma unroll
  for (int i = 0; i < 4; ++i) {
    int i4 = tid + i * 256;                // float4 index 0..1023
    int d = i4 >> 1, eh = (i4 & 1) * 4;
    float4 vr = ((const float4*)Wr)[i4];
    float4 vn = ((const float4*)Wn)[i4];
    *(float4*)&WrS[d * 8 + (d >> 5) * 8 + eh] = vr;
    *(float4*)&WnS[d * 8 + (d >> 5) * 8 + eh] = vn;
  }
  __syncthreads();

  const int w = tid >> 6, lane = tid & 63;
  const int tl = lane & 3, dq = lane >> 2;     // token-in-wave, d-slice
  const int t = blockIdx.x * 16 + w * 4 + tl;

  const float* xp = x + (size_t)t * DIM + dq * 32;
  float xv[32];
#pragma unroll
  for (int i = 0; i < 8; ++i) {
    float4 f = *(const float4*)(xp + i * 4);
    xv[i * 4 + 0] = f.x; xv[i * 4 + 1] = f.y; xv[i * 4 + 2] = f.z; xv[i * 4 + 3] = f.w;
  }

  double accR[8], accN[8];
#pragma unroll
  for (int e2 = 0; e2 < 8; ++e2) { accR[e2] = 0.0; accN[e2] = 0.0; }

#pragma unroll
  for (int r = 0; r < 32; ++r) {
    int d = dq * 32 + r;
    const float* wr = &WrS[d * 8 + (d >> 5) * 8];
    const float* wn = &WnS[d * 8 + (d >> 5) * 8];
    double xd = (double)xv[r];
#pragma unroll
    for (int e2 = 0; e2 < 8; ++e2) {
      accR[e2] += xd * (double)wr[e2];
      accN[e2] += xd * (double)wn[e2];
    }
  }
#pragma unroll
  for (int m = 4; m <= 32; m <<= 1) {
#pragma unroll
    for (int e2 = 0; e2 < 8; ++e2) {
      accR[e2] += __shfl_xor(accR[e2], m);
      accN[e2] += __shfl_xor(accN[e2], m);
    }
  }

  const int el = (lane >> 2) & 7;
  double accRm = 0.0, accNm = 0.0;
#pragma unroll
  for (int e2 = 0; e2 < 8; ++e2) {
    double vR = __shfl(accR[e2], tl);
    double vN = __shfl(accN[e2], tl);
    if (e2 == el) { accRm = vR; accNm = vN; }
  }
  double noisy = -1.0e308;
  if (lane < 32) {
    double logit = accRm + (double)br[el];
    double nlin  = accNm + (double)bn[el];
    double noise = (double)jax_normal_at((uint32_t)t * 8u + (uint32_t)el);
    double sp = fmax(nlin, 0.0) + log1p(exp(-fabs(nlin)));
    noisy = logit + noise * sp;
  }
  double v[8];
#pragma unroll
  for (int e2 = 0; e2 < 8; ++e2) v[e2] = __shfl(noisy, tl + 4 * e2);

  if (lane < 4) {
    int i1 = 0; double v1 = v[0];
#pragma unroll
    for (int e2 = 1; e2 < 8; ++e2) if (v[e2] > v1) { v1 = v[e2]; i1 = e2; }
    int i2 = -1; double v2 = -1.0e308;
#pragma unroll
    for (int e2 = 0; e2 < 8; ++e2) if (e2 != i1 && v[e2] > v2) { v2 = v[e2]; i2 = e2; }
    double w2 = exp(v2 - v1);
    double s = 1.0 + w2;
    float g1 = (float)(1.0 / s), g2 = (float)(w2 / s);
    int p1 = atomicAdd(&fill[i1], 1);
    ltok[i1 * ECAP + p1] = t; lgate[i1 * ECAP + p1] = g1;
    int p2 = atomicAdd(&fill[i2], 1);
    ltok[i2 * ECAP + p2] = t; lgate[i2 * ECAP + p2] = g2;
  }
}

// ---------------- Fused MFMA expert FFN v6 ------------------------------------
// R3-proven structure: M=64/block, 8 waves, GEMM1 weights via wave-private
// glds ring (3 x 2KB, counted vmcnt). NEW: GEMM2 weights via plain
// global->VGPR double-buffered loads (separate VMEM path from the DMA engine);
// next-hc G1 stages issued at G2 ks2=14/15 so they fly across the Hs barrier.
__global__ __launch_bounds__(512) void expert_mfma(
    const float* __restrict__ x,
    const __bf16* __restrict__ W1p, const float* __restrict__ b1,
    const __bf16* __restrict__ W2p, const float* __restrict__ b2,
    const int* __restrict__ fill,
    const int* __restrict__ ltok, const float* __restrict__ lgate,
    float* __restrict__ out) {
  const int e = blockIdx.x & 7;          // XCD-pinned expert
  const int tslot = blockIdx.x >> 3;     // 0..63

  __shared__ __bf16 Xs[64 * 512];        // 64 KB  [tok][ko^(tok&31)][j]
  __shared__ __bf16 Hs[64 * 256];        // 32 KB  [tok][koH^(tok&31)][j]
  __shared__ __bf16 Ring[8][3][1024];    // 48 KB  wave-private rings (2KB slots)
  __shared__ int   toks[64];
  __shared__ float gates[64];

  const int tid  = threadIdx.x;
  const int lane = tid & 63;
  const int w    = tid >> 6;
  const int hi   = lane >> 5;
  const int lm   = lane & 31;

  const int cnt = fill[e];
  const int off = e * ECAP;

  const __bf16* W1e = W1p + (size_t)e * (64 * 64 * 256);
  const __bf16* W2e = W2p + (size_t)e * (16 * 256 * 256);
  __bf16* ringW = &Ring[w][0][0];

  const float b2r0 = b2[e * DIM + (2 * w + 0) * 32 + lm];
  const float b2r1 = b2[e * DIM + (2 * w + 1) * 32 + lm];

  // G1 stage (hc, ss): wave's n-tile nt = hc*8+w, k-octets 4ss..4ss+3 (2KB)
  auto issueG1 = [&](int hc, int ss, int slot) {
    const __bf16* src = W1e + ((size_t)((hc * 8 + w) * 64 + ss * 4)) * 256 + lane * 8;
    __bf16* dst = ringW + slot * 1024;
    glds16(src, dst);
    glds16(src + 512, dst + 512);
  };

  int is_ = 0, cs = 0;

  for (int tile = tslot; tile * 64 < cnt; tile += 64) {
    int start = tile * 64;
    int nrow = min(64, cnt - start);
    int base = off + start;

    // pre-issue hc=0 stages 0,1 (wave-private, safe pre-barrier)
    issueG1(0, 0, is_); ADV3(is_);
    issueG1(0, 1, is_); ADV3(is_);

    SBAR;                                // prev tile's epilogue done with toks/gates
    if (tid < 64) {
      int tk = 0; float g = 0.f;
      if (tid < nrow) { tk = ltok[base + tid]; g = lgate[base + tid]; }
      toks[tid] = tk; gates[tid] = g;
    }
    WAITLGKM0; SBAR;

    // stage X tile: fp32 global -> bf16 LDS (A-frag layout, 32-slot XOR swizzle)
    {
      int tm = tid >> 3, seg = tid & 7;
      bool valid = tm < nrow;
      const float* xp = x + (size_t)(valid ? toks[tm] : toks[0]) * DIM + seg * 64;
#pragma unroll
      for (int s2 = 0; s2 < 8; ++s2) {
        bf16x8 v;
        if (valid) {
          float4 f0 = *(const float4*)(xp + s2 * 8);
          float4 f1 = *(const float4*)(xp + s2 * 8 + 4);
          v[0] = (__bf16)f0.x; v[1] = (__bf16)f0.y; v[2] = (__bf16)f0.z; v[3] = (__bf16)f0.w;
          v[4] = (__bf16)f1.x; v[5] = (__bf16)f1.y; v[6] = (__bf16)f1.z; v[7] = (__bf16)f1.w;
        } else {
#pragma unroll
          for (int j = 0; j < 8; ++j) v[j] = (__bf16)0.f;
        }
        int ko = seg * 8 + s2;
        *(bf16x8*)&Xs[((size_t)tm * 64 + (ko ^ (tm & 31))) * 8] = v;
      }
    }
    WAITLGKM0; SBAR;                     // Xs ready

    f32x16 acc200, acc201, acc210, acc211;
#pragma unroll
    for (int r = 0; r < 16; ++r) { acc200[r] = 0.f; acc201[r] = 0.f; acc210[r] = 0.f; acc211[r] = 0.f; }

    for (int hc = 0; hc < 8; ++hc) {
      float bias = b1[e * HID + (hc * 8 + w) * 32 + lm];
      f32x16 acc10, acc11;
#pragma unroll
      for (int r = 0; r < 16; ++r) { acc10[r] = 0.f; acc11[r] = 0.f; }

      // ---- GEMM1: 16 glds-ring stages (K = 512) ----
#pragma unroll
      for (int ss = 0; ss < 16; ++ss) {
        if (ss < 14)      { issueG1(hc, ss + 2, is_); ADV3(is_); WAITVM(4); }
        else if (ss == 14){ WAITVM(2); }
        else              { WAITVM(0); }
        SCHEDB;
        const __bf16* rb = ringW + cs * 1024; ADV3(cs);
#pragma unroll
        for (int kk = 0; kk < 2; ++kk) {
          int koX = (ss * 2 + kk) * 2 + hi;
          bf16x8 a0 = *(const bf16x8*)&Xs[((size_t)lm * 64 + (koX ^ lm)) * 8];
          bf16x8 a1 = *(const bf16x8*)&Xs[((size_t)(32 + lm) * 64 + (koX ^ lm)) * 8];
          bf16x8 b  = *(const bf16x8*)&rb[kk * 512 + hi * 256 + lm * 8];
          acc10 = mfma32(a0, b, acc10);
          acc11 = mfma32(a1, b, acc11);
        }
      }

      // ---- bias + relu -> Hs (A-frag layout for GEMM2) ----
#pragma unroll
      for (int m = 0; m < 2; ++m)
#pragma unroll
        for (int r = 0; r < 16; ++r) {
          int tok = (r & 3) + 8 * (r >> 2) + 4 * hi + 32 * m;
          float v = fmaxf((m ? acc11[r] : acc10[r]) + bias, 0.f);
          int koW = (w * 4 + (lm >> 3)) ^ (tok & 31);
          Hs[((size_t)tok * 32 + koW) * 8 + (lm & 7)] = (__bf16)v;
        }
      WAITLGKM0; SBAR;                   // Hs ready for all waves

      // ---- GEMM2: plain global->VGPR double-buffered weights ----
      const __bf16* w2l = W2e + (size_t)(2 * w) * 65536 + (size_t)(hc * 32 + hi) * 256 + lm * 8;
      bf16x8 cb0 = *(const bf16x8*)(w2l);
      bf16x8 cb1 = *(const bf16x8*)(w2l + 65536);
#pragma unroll
      for (int ks2 = 0; ks2 < 16; ++ks2) {
        bf16x8 nb0, nb1;
        if (ks2 < 15) {
          nb0 = *(const bf16x8*)(w2l + (ks2 + 1) * 512);
          nb1 = *(const bf16x8*)(w2l + 65536 + (ks2 + 1) * 512);
        }
        if (hc < 7) {                    // next-hc G1 prefetch flies over the barrier
          if (ks2 == 14) { issueG1(hc + 1, 0, is_); ADV3(is_); }
          if (ks2 == 15) { issueG1(hc + 1, 1, is_); ADV3(is_); }
        }
        int koH = ks2 * 2 + hi;
        bf16x8 h0 = *(const bf16x8*)&Hs[((size_t)lm * 32 + (koH ^ lm)) * 8];
        bf16x8 h1 = *(const bf16x8*)&Hs[((size_t)(32 + lm) * 32 + (koH ^ lm)) * 8];
        acc200 = mfma32(h0, cb0, acc200);
        acc201 = mfma32(h1, cb0, acc201);
        acc210 = mfma32(h0, cb1, acc210);
        acc211 = mfma32(h1, cb1, acc211);
        if (ks2 < 15) { cb0 = nb0; cb1 = nb1; }
      }
      SBAR;                              // all waves done reading Hs before rewrite
    }

    // ---- epilogue: gate-weighted atomic accumulate, d-coalesced ----
    {
      int d0 = (2 * w) * 32 + lm;
      int d1 = (2 * w + 1) * 32 + lm;
#pragma unroll
      for (int m = 0; m < 2; ++m)
#pragma unroll
        for (int r = 0; r < 16; ++r) {
          int row = (r & 3) + 8 * (r >> 2) + 4 * hi + 32 * m;
          int tk = toks[row];
          float gg = gates[row];
          float* op = out + (size_t)tk * DIM;
          atomicAdd(op + d0, gg * ((m ? acc201[r] : acc200[r]) + b2r0));
          atomicAdd(op + d1, gg * ((m ? acc211[r] : acc210[r]) + b2r1));
        }
    }
  }
}

extern "C" void kernel_launch(void* const* d_in, const int* in_sizes, int n_in,
                              void* d_out, int out_size, void* d_ws, size_t ws_size,
                              hipStream_t stream) {
  const float* x  = (const float*)d_in[0];
  const float* Wr = (const float*)d_in[1];
  const float* br = (const float*)d_in[2];
  const float* Wn = (const float*)d_in[3];
  const float* bn = (const float*)d_in[4];
  const float* W1 = (const float*)d_in[5];
  const float* b1 = (const float*)d_in[6];
  const float* W2 = (const float*)d_in[7];
  const float* b2 = (const float*)d_in[8];
  float* out = (float*)d_out;

  uint8_t* wsb = (uint8_t*)d_ws;
  int* fill     = (int*)(wsb);                        // 32 B
  int* ltok     = (int*)(wsb + 4096);                 // 8*6144*4 = 196608 B
  float* lgate  = (float*)(wsb + 4096 + 196608);      // 196608 B
  __bf16* W1p   = (__bf16*)(wsb + 401408);            // 16 MB
  __bf16* W2p   = (__bf16*)(wsb + 401408 + 16777216); // 16 MB
  // total ws usage: 401408 + 2*16777216 = 33,955,840 bytes (within prior 34.1 MB)

  prep_kernel<<<4096, 256, 0, stream>>>(W1, W2, W1p, W2p, out, fill);
  router_kernel<<<T_TOKENS / 16, 256, 0, stream>>>(x, Wr, br, Wn, bn, fill, ltok, lgate);
  expert_mfma<<<512, 512, 0, stream>>>(x, W1p, b1, W2p, b2, fill, ltok, lgate, out);
}

// Round 7
// 521.324 us; speedup vs baseline: 1.8886x; 1.2888x over previous
//
#include <hip/hip_runtime.h>
#include <hip/hip_bf16.h>
#include <stdint.h>
#include <math.h>

#define T_TOKENS 16384
#define DIM      512
#define NEXP     8
#define HID      2048

typedef __attribute__((ext_vector_type(8))) __bf16 bf16x8;
typedef __attribute__((ext_vector_type(16))) float f32x16;

__device__ __forceinline__ f32x16 mfma32(bf16x8 a, bf16x8 b, f32x16 c) {
  return __builtin_amdgcn_mfma_f32_32x32x16_bf16(a, b, c, 0, 0, 0);
}

// async global->LDS DMA, 16B/lane; LDS dest = wave-uniform base + lane*16
__device__ __forceinline__ void glds16(const __bf16* g, __bf16* l) {
  __builtin_amdgcn_global_load_lds((const __attribute__((address_space(1))) void*)g,
                                   (__attribute__((address_space(3))) void*)l, 16, 0, 0);
}

#define WAITVM(n) asm volatile("s_waitcnt vmcnt(" #n ")" ::: "memory")
#define WAITLGKM0 asm volatile("s_waitcnt lgkmcnt(0)" ::: "memory")
#define SBAR      asm volatile("s_barrier" ::: "memory")
#define SCHEDB    __builtin_amdgcn_sched_barrier(0)
#define ADV3(v)   v = ((v) == 2) ? 0 : ((v) + 1)

// ---- JAX threefry2x32, key = (0, 42) ----
__device__ __forceinline__ void threefry2x32(uint32_t k0, uint32_t k1,
                                             uint32_t x0, uint32_t x1,
                                             uint32_t* o0, uint32_t* o1) {
  uint32_t ks0 = k0, ks1 = k1, ks2 = k0 ^ k1 ^ 0x1BD11BDAu;
#define TF_ROT(v, d) (((v) << (d)) | ((v) >> (32 - (d))))
#define TF_ROUND(r) { x0 += x1; x1 = TF_ROT(x1, r); x1 ^= x0; }
  x0 += ks0; x1 += ks1;
  TF_ROUND(13) TF_ROUND(15) TF_ROUND(26) TF_ROUND(6)
  x0 += ks1; x1 += ks2 + 1u;
  TF_ROUND(17) TF_ROUND(29) TF_ROUND(16) TF_ROUND(24)
  x0 += ks2; x1 += ks0 + 2u;
  TF_ROUND(13) TF_ROUND(15) TF_ROUND(26) TF_ROUND(6)
  x0 += ks0; x1 += ks1 + 3u;
  TF_ROUND(17) TF_ROUND(29) TF_ROUND(16) TF_ROUND(24)
  x0 += ks1; x1 += ks2 + 4u;
  TF_ROUND(13) TF_ROUND(15) TF_ROUND(26) TF_ROUND(6)
  x0 += ks2; x1 += ks0 + 5u;
#undef TF_ROUND
#undef TF_ROT
  *o0 = x0; *o1 = x1;
}

// ---- XLA ErfInv32 (Giles polynomial) ----
__device__ __forceinline__ float erfinv_xla(float x) {
  float w = -log1pf(__fmul_rn(-x, x));
  float p;
  if (w < 5.0f) {
    w = __fadd_rn(w, -2.5f);
    p = 2.81022636e-08f;
    p = __fadd_rn(3.43273939e-07f, __fmul_rn(p, w));
    p = __fadd_rn(-3.5233877e-06f, __fmul_rn(p, w));
    p = __fadd_rn(-4.39150654e-06f, __fmul_rn(p, w));
    p = __fadd_rn(0.00021858087f, __fmul_rn(p, w));
    p = __fadd_rn(-0.00125372503f, __fmul_rn(p, w));
    p = __fadd_rn(-0.00417768164f, __fmul_rn(p, w));
    p = __fadd_rn(0.246640727f, __fmul_rn(p, w));
    p = __fadd_rn(1.50140941f, __fmul_rn(p, w));
  } else {
    w = __fadd_rn(sqrtf(w), -3.0f);
    p = -0.000200214257f;
    p = __fadd_rn(0.000100950558f, __fmul_rn(p, w));
    p = __fadd_rn(0.00134934322f, __fmul_rn(p, w));
    p = __fadd_rn(-0.00367342844f, __fmul_rn(p, w));
    p = __fadd_rn(0.00573950773f, __fmul_rn(p, w));
    p = __fadd_rn(-0.0076224613f, __fmul_rn(p, w));
    p = __fadd_rn(0.00943887047f, __fmul_rn(p, w));
    p = __fadd_rn(1.00167406f, __fmul_rn(p, w));
    p = __fadd_rn(2.83297682f, __fmul_rn(p, w));
  }
  return __fmul_rn(p, x);
}

__device__ __forceinline__ float jax_normal_at(uint32_t i) {
  uint32_t o0, o1;
  threefry2x32(0u, 42u, 0u, i, &o0, &o1);
  uint32_t bits = o0 ^ o1;
  float f = __fadd_rn(__uint_as_float((bits >> 9) | 0x3f800000u), -1.0f);
  const float lo = -0.99999994f;
  float u = fmaxf(lo, __fadd_rn(__fmul_rn(f, 2.0f), lo));
  return __fmul_rn(1.4142135623730951f, erfinv_xla(u));
}

// ============ Kernel 1: zero-out + weight pack + router (one dispatch) ======
// 4096 blocks x 256 threads. Every block: zero slice of out + pack one 64x64
// weight tile. Blocks 0..255 additionally route a 64-token slice, writing
// per-slice segments ltok2[slice][e][<=64] (pure writes - no global zeroing
// needed) + fillRow[slice][e] counts. Entry = token(14b) | gate_q18(18b).
__global__ __launch_bounds__(256) void prep_router(
    const float* __restrict__ x, const float* __restrict__ Wr, const float* __restrict__ br,
    const float* __restrict__ Wn, const float* __restrict__ bn,
    const float* __restrict__ W1, const float* __restrict__ W2,
    __bf16* __restrict__ W1p, __bf16* __restrict__ W2p,
    uint8_t* __restrict__ fillRow, uint32_t* __restrict__ ltok2,
    float* __restrict__ out) {
  __shared__ float Ls[64][68];
  __shared__ float WrS[4224], WnS[4224];   // 512*8 + 16*8 pad
  __shared__ int lhist[8];
  const int tid = threadIdx.x;
  const int blk = blockIdx.x;

  // ---- zero out: 2M float4 over 4096 blocks ----
  {
    float4 z = {0.f, 0.f, 0.f, 0.f};
    ((float4*)out)[blk * 512 + tid] = z;
    ((float4*)out)[blk * 512 + 256 + tid] = z;
  }

  // ---- transpose-pack tile: dst[e][nt][ko][lc][j] = src[e][ko*8+j][nt*32+lc]
  {
    const float* src; __bf16* dst; int R, C, e, rt, ct;
    if (blk < 2048) { e = blk >> 8; int rem = blk & 255; rt = rem >> 5; ct = rem & 31;
                      src = W1; dst = W1p; R = 512; C = 2048; }
    else            { int v2 = blk - 2048; e = v2 >> 8; int rem = v2 & 255; rt = rem >> 3; ct = rem & 7;
                      src = W2; dst = W2p; R = 2048; C = 512; }
    const float* sp = src + (size_t)e * R * C + (size_t)(rt * 64) * C + ct * 64;
    int row = tid >> 4, col = (tid & 15) * 4;
#pragma unroll
    for (int it = 0; it < 4; ++it)
      *(float4*)&Ls[it * 16 + row][col] = *(const float4*)(sp + (size_t)(it * 16 + row) * C + col);
    __syncthreads();
    int KO = R >> 3;
#pragma unroll
    for (int q = 0; q < 2; ++q) {
      int f = tid + q * 256;
      int lc = f & 31, kol = (f >> 5) & 7, ntl = f >> 8;
      bf16x8 vv;
#pragma unroll
      for (int j = 0; j < 8; ++j) vv[j] = (__bf16)Ls[kol * 8 + j][ntl * 32 + lc];
      size_t idx = ((size_t)(e * (C >> 5) + ct * 2 + ntl) * KO + rt * 8 + kol) * 256 + lc * 8;
      *(bf16x8*)(dst + idx) = vv;
    }
  }

  if (blk >= 256) return;

  // ---- router: this block's 64-token slice ----
#pragma unroll
  for (int i = 0; i < 4; ++i) {
    int i4 = tid + i * 256;                // float4 index 0..1023
    int d = i4 >> 1, eh = (i4 & 1) * 4;
    *(float4*)&WrS[d * 8 + (d >> 5) * 8 + eh] = ((const float4*)Wr)[i4];
    *(float4*)&WnS[d * 8 + (d >> 5) * 8 + eh] = ((const float4*)Wn)[i4];
  }
  if (tid < 8) lhist[tid] = 0;
  __syncthreads();

  const int w = tid >> 6, lane = tid & 63;
  const int tl = lane & 3, dq = lane >> 2;
  const int el = (lane >> 2) & 7;

  for (int p = 0; p < 4; ++p) {
    int t = blk * 64 + p * 16 + w * 4 + tl;

    const float* xp = x + (size_t)t * DIM + dq * 32;
    float xv[32];
#pragma unroll
    for (int i = 0; i < 8; ++i) {
      float4 f = *(const float4*)(xp + i * 4);
      xv[i * 4 + 0] = f.x; xv[i * 4 + 1] = f.y; xv[i * 4 + 2] = f.z; xv[i * 4 + 3] = f.w;
    }

    double accR[8], accN[8];
#pragma unroll
    for (int e2 = 0; e2 < 8; ++e2) { accR[e2] = 0.0; accN[e2] = 0.0; }
#pragma unroll
    for (int r = 0; r < 32; ++r) {
      int d = dq * 32 + r;
      const float* wr = &WrS[d * 8 + (d >> 5) * 8];
      const float* wn = &WnS[d * 8 + (d >> 5) * 8];
      double xd = (double)xv[r];
#pragma unroll
      for (int e2 = 0; e2 < 8; ++e2) {
        accR[e2] += xd * (double)wr[e2];
        accN[e2] += xd * (double)wn[e2];
      }
    }
#pragma unroll
    for (int m = 4; m <= 32; m <<= 1) {
#pragma unroll
      for (int e2 = 0; e2 < 8; ++e2) {
        accR[e2] += __shfl_xor(accR[e2], m);
        accN[e2] += __shfl_xor(accN[e2], m);
      }
    }

    double accRm = 0.0, accNm = 0.0;
#pragma unroll
    for (int e2 = 0; e2 < 8; ++e2) {
      double vR = __shfl(accR[e2], tl);
      double vN = __shfl(accN[e2], tl);
      if (e2 == el) { accRm = vR; accNm = vN; }
    }
    double noisy = -1.0e308;
    if (lane < 32) {
      double logit = accRm + (double)br[el];
      double nlin  = accNm + (double)bn[el];
      double noise = (double)jax_normal_at((uint32_t)t * 8u + (uint32_t)el);
      double sp = fmax(nlin, 0.0) + log1p(exp(-fabs(nlin)));
      noisy = logit + noise * sp;
    }
    double v[8];
#pragma unroll
    for (int e2 = 0; e2 < 8; ++e2) v[e2] = __shfl(noisy, tl + 4 * e2);

    if (lane < 4) {
      int i1 = 0; double v1 = v[0];
#pragma unroll
      for (int e2 = 1; e2 < 8; ++e2) if (v[e2] > v1) { v1 = v[e2]; i1 = e2; }
      int i2 = -1; double v2 = -1.0e308;
#pragma unroll
      for (int e2 = 0; e2 < 8; ++e2) if (e2 != i1 && v[e2] > v2) { v2 = v[e2]; i2 = e2; }
      double w2 = exp(v2 - v1);
      double s = 1.0 + w2;
      uint32_t q1 = (uint32_t)((1.0 / s) * 262143.0 + 0.5);
      uint32_t q2 = (uint32_t)((w2 / s) * 262143.0 + 0.5);
      int p1 = atomicAdd(&lhist[i1], 1);
      ltok2[(blk * 8 + i1) * 64 + p1] = (uint32_t)t | (q1 << 14);
      int p2 = atomicAdd(&lhist[i2], 1);
      ltok2[(blk * 8 + i2) * 64 + p2] = (uint32_t)t | (q2 << 14);
    }
  }
  __syncthreads();
  if (tid < 8) fillRow[blk * 8 + tid] = (uint8_t)lhist[tid];
}

// ============ Kernel 2: expert FFN (R3-proven ring schedule) ================
// M=64/block, 8 waves. Weights stream through wave-private glds rings
// (3 x 2KB, counted vmcnt(4), never drained in-loop). Per-expert contiguous
// token order reconstructed via 256-entry LDS scan + binary search.
__global__ __launch_bounds__(512) void expert_mfma(
    const float* __restrict__ x,
    const __bf16* __restrict__ W1p, const float* __restrict__ b1,
    const __bf16* __restrict__ W2p, const float* __restrict__ b2,
    const uint8_t* __restrict__ fillRow, const uint32_t* __restrict__ ltok2,
    float* __restrict__ out) {
  const int e = blockIdx.x & 7;          // XCD-pinned expert
  const int tslot = blockIdx.x >> 3;     // 0..63

  __shared__ __bf16 Xs[64 * 512];        // 64 KB  [tok][ko^(tok&31)][j]
  __shared__ __bf16 Hs[64 * 256];        // 32 KB  [tok][koH^(tok&31)][j]
  __shared__ __bf16 Ring[8][3][1024];    // 48 KB  wave-private rings (2KB slots)
  __shared__ int   toks[64];
  __shared__ float gates[64];
  __shared__ int   scanS[256];           // inclusive scan of fillRow[.][e]

  const int tid  = threadIdx.x;
  const int lane = tid & 63;
  const int w    = tid >> 6;
  const int hi   = lane >> 5;
  const int lm   = lane & 31;

  // ---- inclusive scan over the 256 slice counts for this expert ----
  if (tid < 256) scanS[tid] = (int)fillRow[tid * 8 + e];
  __syncthreads();
  for (int d2 = 1; d2 < 256; d2 <<= 1) {
    int a = 0;
    if (tid < 256 && tid >= d2) a = scanS[tid - d2];
    __syncthreads();
    if (tid < 256 && tid >= d2) scanS[tid] += a;
    __syncthreads();
  }
  const int cnt = scanS[255];

  const __bf16* W1e = W1p + (size_t)e * (64 * 64 * 256);
  const __bf16* W2e = W2p + (size_t)e * (16 * 256 * 256);
  __bf16* ringW = &Ring[w][0][0];

  const float b2r0 = b2[e * DIM + (2 * w + 0) * 32 + lm];
  const float b2r1 = b2[e * DIM + (2 * w + 1) * 32 + lm];

  // sub-stage g (0..255): hc=g>>5; phase=(g>>4)&1; ss=g&15
  auto issueStage = [&](int g, int slot) {
    int hc = g >> 5, ss = g & 15;
    __bf16* dstL = ringW + slot * 1024;
    if (((g >> 4) & 1) == 0) {
      int nt = hc * 8 + w;
      const __bf16* srcp = W1e + ((size_t)(nt * 64 + ss * 4)) * 256 + lane * 8;
      glds16(srcp, dstL);
      glds16(srcp + 512, dstL + 512);
    } else {
      int ko2 = hc * 32 + ss * 2;
      glds16(W2e + ((size_t)((2 * w) * 256 + ko2)) * 256 + lane * 8, dstL);
      glds16(W2e + ((size_t)((2 * w + 1) * 256 + ko2)) * 256 + lane * 8, dstL + 512);
    }
  };

  for (int tile = tslot; tile * 64 < cnt; tile += 64) {
    int start = tile * 64;
    int nrow = min(64, cnt - start);

    // fire this tile's first two weight stages (wave-private, safe pre-barrier)
    issueStage(0, 0);
    issueStage(1, 1);

    SBAR;                                // prev tile's epilogue done with toks/gates
    if (tid < 64) {
      int tk = 0; float g = 0.f;
      if (tid < nrow) {
        int rank = start + tid;
        int s = 0;                       // largest s with exclusive(s) <= rank
#pragma unroll
        for (int st = 128; st; st >>= 1) {
          int t2 = s + st;
          if (t2 < 256 && scanS[t2 - 1] <= rank) s = t2;
        }
        int ex = s ? scanS[s - 1] : 0;
        uint32_t en = ltok2[(s * 8 + e) * 64 + (rank - ex)];
        tk = (int)(en & 16383u);
        g = (float)(en >> 14) * (1.f / 262143.f);
      }
      toks[tid] = tk; gates[tid] = g;
    }
    WAITLGKM0; SBAR;

    // stage X tile: fp32 global -> bf16 LDS (A-frag layout, 32-slot XOR swizzle)
    {
      int tm = tid >> 3, seg = tid & 7;
      bool valid = tm < nrow;
      const float* xp = x + (size_t)(valid ? toks[tm] : toks[0]) * DIM + seg * 64;
#pragma unroll
      for (int s2 = 0; s2 < 8; ++s2) {
        bf16x8 v;
        if (valid) {
          float4 f0 = *(const float4*)(xp + s2 * 8);
          float4 f1 = *(const float4*)(xp + s2 * 8 + 4);
          v[0] = (__bf16)f0.x; v[1] = (__bf16)f0.y; v[2] = (__bf16)f0.z; v[3] = (__bf16)f0.w;
          v[4] = (__bf16)f1.x; v[5] = (__bf16)f1.y; v[6] = (__bf16)f1.z; v[7] = (__bf16)f1.w;
        } else {
#pragma unroll
          for (int j = 0; j < 8; ++j) v[j] = (__bf16)0.f;
        }
        int ko = seg * 8 + s2;
        *(bf16x8*)&Xs[((size_t)tm * 64 + (ko ^ (tm & 31))) * 8] = v;
      }
    }
    WAITLGKM0; SBAR;                     // Xs ready

    f32x16 acc200, acc201, acc210, acc211;
#pragma unroll
    for (int r = 0; r < 16; ++r) { acc200[r] = 0.f; acc201[r] = 0.f; acc210[r] = 0.f; acc211[r] = 0.f; }

    int cs = 0, is_ = 2;

    for (int hc = 0; hc < 8; ++hc) {
      float bias = b1[e * HID + (hc * 8 + w) * 32 + lm];
      f32x16 acc10, acc11;
#pragma unroll
      for (int r = 0; r < 16; ++r) { acc10[r] = 0.f; acc11[r] = 0.f; }

      // ---- GEMM1: 16 sub-stages (K = 512) ----
#pragma unroll
      for (int ss = 0; ss < 16; ++ss) {
        issueStage(hc * 32 + ss + 2, is_); ADV3(is_);
        WAITVM(4); SCHEDB;
        const __bf16* rb = ringW + cs * 1024; ADV3(cs);
#pragma unroll
        for (int kk = 0; kk < 2; ++kk) {
          int koX = (ss * 2 + kk) * 2 + hi;
          bf16x8 a0 = *(const bf16x8*)&Xs[((size_t)lm * 64 + (koX ^ lm)) * 8];
          bf16x8 a1 = *(const bf16x8*)&Xs[((size_t)(32 + lm) * 64 + (koX ^ lm)) * 8];
          bf16x8 b  = *(const bf16x8*)&rb[kk * 512 + hi * 256 + lm * 8];
          acc10 = mfma32(a0, b, acc10);
          acc11 = mfma32(a1, b, acc11);
        }
      }

      // ---- bias + relu -> Hs (A-frag layout for GEMM2) ----
#pragma unroll
      for (int m = 0; m < 2; ++m)
#pragma unroll
        for (int r = 0; r < 16; ++r) {
          int tok = (r & 3) + 8 * (r >> 2) + 4 * hi + 32 * m;
          float v = fmaxf((m ? acc11[r] : acc10[r]) + bias, 0.f);
          int koW = (w * 4 + (lm >> 3)) ^ (tok & 31);
          Hs[((size_t)tok * 32 + koW) * 8 + (lm & 7)] = (__bf16)v;
        }
      WAITLGKM0; SBAR;                   // Hs ready for all waves

      // ---- GEMM2: 16 sub-stages (k-chunk of 256) ----
#pragma unroll
      for (int ss = 0; ss < 16; ++ss) {
        if (hc < 7 || ss < 14) { issueStage(hc * 32 + 16 + ss + 2, is_); ADV3(is_); }
        if (hc < 7 || ss < 14) { WAITVM(4); }
        else if (ss == 14)     { WAITVM(2); }
        else                   { WAITVM(0); }
        SCHEDB;
        const __bf16* rb = ringW + cs * 1024; ADV3(cs);
        int koH = ss * 2 + hi;
        bf16x8 h0  = *(const bf16x8*)&Hs[((size_t)lm * 32 + (koH ^ lm)) * 8];
        bf16x8 h1  = *(const bf16x8*)&Hs[((size_t)(32 + lm) * 32 + (koH ^ lm)) * 8];
        bf16x8 b0  = *(const bf16x8*)&rb[hi * 256 + lm * 8];
        bf16x8 b1v = *(const bf16x8*)&rb[512 + hi * 256 + lm * 8];
        acc200 = mfma32(h0, b0, acc200);
        acc201 = mfma32(h1, b0, acc201);
        acc210 = mfma32(h0, b1v, acc210);
        acc211 = mfma32(h1, b1v, acc211);
      }
      SBAR;                              // all waves done reading Hs before rewrite
    }

    // ---- epilogue: gate-weighted atomic accumulate, d-coalesced ----
    {
      int d0 = (2 * w) * 32 + lm;
      int d1 = (2 * w + 1) * 32 + lm;
#pragma unroll
      for (int m = 0; m < 2; ++m)
#pragma unroll
        for (int r = 0; r < 16; ++r) {
          int row = (r & 3) + 8 * (r >> 2) + 4 * hi + 32 * m;
          int tk = toks[row];
          float gg = gates[row];
          float* op = out + (size_t)tk * DIM;
          atomicAdd(op + d0, gg * ((m ? acc201[r] : acc200[r]) + b2r0));
          atomicAdd(op + d1, gg * ((m ? acc211[r] : acc210[r]) + b2r1));
        }
    }
  }
}

extern "C" void kernel_launch(void* const* d_in, const int* in_sizes, int n_in,
                              void* d_out, int out_size, void* d_ws, size_t ws_size,
                              hipStream_t stream) {
  const float* x  = (const float*)d_in[0];
  const float* Wr = (const float*)d_in[1];
  const float* br = (const float*)d_in[2];
  const float* Wn = (const float*)d_in[3];
  const float* bn = (const float*)d_in[4];
  const float* W1 = (const float*)d_in[5];
  const float* b1 = (const float*)d_in[6];
  const float* W2 = (const float*)d_in[7];
  const float* b2 = (const float*)d_in[8];
  float* out = (float*)d_out;

  uint8_t* wsb = (uint8_t*)d_ws;
  uint8_t*  fillRow = wsb;                            // 256*8 u8 = 2048 B
  uint32_t* ltok2   = (uint32_t*)(wsb + 2048);        // 256*8*64*4 = 524288 B
  __bf16*   W1p     = (__bf16*)(wsb + 526336);        // 16 MB
  __bf16*   W2p     = (__bf16*)(wsb + 526336 + 16777216); // 16 MB
  // total ws usage: 526336 + 2*16777216 = 34,080,768 B (<= 34,083,328 proven)

  prep_router<<<4096, 256, 0, stream>>>(x, Wr, br, Wn, bn, W1, W2, W1p, W2p,
                                        fillRow, ltok2, out);
  expert_mfma<<<512, 512, 0, stream>>>(x, W1p, b1, W2p, b2, fillRow, ltok2, out);
}